// Round 9
// baseline (1512.164 us; speedup 1.0000x reference)
//
#include <hip/hip_runtime.h>
#include <hip/hip_bf16.h>

#define T_TOK 4096
#define HDIM  2048
#define NEXP  64
#define IDIM  768
#define TOPK  4
#define CAPE  512
#define NFLAT (T_TOK*TOPK)

typedef __bf16        bf16x8 __attribute__((ext_vector_type(8)));
typedef float         f32x4  __attribute__((ext_vector_type(4)));
typedef unsigned int  u32x4  __attribute__((ext_vector_type(4)));

__device__ __forceinline__ unsigned short f2bf(float f) {
  __bf16 b = (__bf16)f;
  return __builtin_bit_cast(unsigned short, b);
}
__device__ __forceinline__ unsigned pack2(float lo, float hi) {
  return (unsigned)f2bf(lo) | ((unsigned)f2bf(hi) << 16);
}
// LDS addr: row stripe of 128B, 16B chunk xor-swizzled (conflict-free frag reads)
__device__ __forceinline__ int swz(int row, int chunk) {
  return row*128 + (((chunk ^ (row & 7) ^ ((row >> 3) & 7)) & 7) << 4);
}
// async global->LDS, 16B per lane; LDS dest linear, source pre-swizzled.
__device__ __forceinline__ void gload_lds16(const void* g, void* l) {
  __builtin_amdgcn_global_load_lds(
      (const __attribute__((address_space(1))) unsigned int*)g,
      (__attribute__((address_space(3))) unsigned int*)l, 16, 0, 0);
}

// ---------------- gating: logits, top-4, renorm weights; also hs -> bf16 ----------------
__global__ __launch_bounds__(256) void k_gating(
    const float* __restrict__ hs, const float* __restrict__ gw,
    unsigned short* __restrict__ hs_bf, int* __restrict__ tidx, float* __restrict__ tw)
{
  __shared__ float lg[16][64];
  const int tid = threadIdx.x;
  const int t0  = blockIdx.x * 16;

  {
    const f32x4* src = (const f32x4*)(hs + (size_t)t0 * HDIM);
    for (int i = tid; i < 16 * HDIM / 4; i += 256) {
      f32x4 v = src[i];
      ushort4 o;
      o.x = f2bf(v[0]); o.y = f2bf(v[1]); o.z = f2bf(v[2]); o.w = f2bf(v[3]);
      *(ushort4*)(hs_bf + (size_t)t0 * HDIM + (size_t)i * 4) = o;
    }
  }

  const int lane = tid & 63, wv = tid >> 6;
  {
    const f32x4* gr = (const f32x4*)(gw + (size_t)lane * HDIM);
    const f32x4* x0 = (const f32x4*)(hs + (size_t)(t0 + wv*4 + 0) * HDIM);
    const f32x4* x1 = (const f32x4*)(hs + (size_t)(t0 + wv*4 + 1) * HDIM);
    const f32x4* x2 = (const f32x4*)(hs + (size_t)(t0 + wv*4 + 2) * HDIM);
    const f32x4* x3 = (const f32x4*)(hs + (size_t)(t0 + wv*4 + 3) * HDIM);
    float a0=0.f, a1=0.f, a2=0.f, a3=0.f;
    for (int h = 0; h < HDIM/4; ++h) {
      f32x4 g = gr[h];
      f32x4 v0 = x0[h], v1 = x1[h], v2 = x2[h], v3 = x3[h];
      a0 += g[0]*v0[0] + g[1]*v0[1] + g[2]*v0[2] + g[3]*v0[3];
      a1 += g[0]*v1[0] + g[1]*v1[1] + g[2]*v1[2] + g[3]*v1[3];
      a2 += g[0]*v2[0] + g[1]*v2[1] + g[2]*v2[2] + g[3]*v2[3];
      a3 += g[0]*v3[0] + g[1]*v3[1] + g[2]*v3[2] + g[3]*v3[3];
    }
    lg[wv*4+0][lane] = a0;
    lg[wv*4+1][lane] = a1;
    lg[wv*4+2][lane] = a2;
    lg[wv*4+3][lane] = a3;
  }
  __syncthreads();

  if (tid < 16) {
    const int t = t0 + tid;
    unsigned long long chosen = 0ull;
    float bv[4]; int bi[4];
#pragma unroll
    for (int k = 0; k < 4; ++k) {
      float best = -1e30f; int b = 0;
      for (int e = 0; e < 64; ++e) {
        float v = lg[tid][e];
        if (!((chosen >> e) & 1ull) && v > best) { best = v; b = e; }
      }
      chosen |= 1ull << b; bv[k] = best; bi[k] = b;
    }
    float s = 0.f, w[4];
#pragma unroll
    for (int k = 0; k < 4; ++k) { w[k] = __expf(bv[k] - bv[0]); s += w[k]; }
    float inv = 1.f / s;
#pragma unroll
    for (int k = 0; k < 4; ++k) { tidx[t*4+k] = bi[k]; tw[t*4+k] = w[k] * inv; }
  }
}

// ---------------- per-expert stable rank (ballot scan) ----------------
__global__ __launch_bounds__(64) void k_count_rank(
    const int* __restrict__ tidx, int* __restrict__ rankb, int* __restrict__ counts)
{
  const int e = blockIdx.x;
  const int lane = threadIdx.x;
  int base = 0;
  for (int c = 0; c < NFLAT/64; ++c) {
    int n = c*64 + lane;
    bool m = (tidx[n] == e);
    unsigned long long mask = __ballot(m);
    if (m) rankb[n] = base + __popcll(mask & ((1ull << lane) - 1ull));
    base += __popcll(mask);
  }
  if (lane == 0) counts[e] = base;
}

// ---------------- starts scan + sorted-row maps ----------------
__global__ __launch_bounds__(256) void k_build(
    const int* __restrict__ tidx, const int* __restrict__ rankb,
    const int* __restrict__ counts,
    int* __restrict__ starts, int* __restrict__ row_info, int* __restrict__ sortpos)
{
  __shared__ int s_starts[NEXP];
  if (threadIdx.x == 0) {
    int s = 0;
    for (int e = 0; e < NEXP; ++e) { s_starts[e] = s; starts[e] = s; s += counts[e]; }
  }
  __syncthreads();
  for (int n = threadIdx.x; n < NFLAT; n += 256) {
    int e = tidx[n], r = rankb[n];
    int sr = s_starts[e] + r;
    row_info[sr] = n;
    sortpos[n] = (r < CAPE) ? sr : -1;
  }
}

// ---------------- GEMM1 (gather A) + fused SwiGLU -> a_buf (bf16) ----------------
// BM=256 rows x 64 icols x {g,u}, BK=64, 256 thr, 48KB LDS single-buffer, 3 blocks/CU.
// Linear block mapping (NO XCD swizzle): e = b/12, nt = b%12.
__global__ __launch_bounds__(256, 3) void k_gemm1(
    const unsigned short* __restrict__ hs_bf, const float* __restrict__ w13,
    const int* __restrict__ counts, const int* __restrict__ starts,
    const int* __restrict__ row_info, unsigned short* __restrict__ a_buf)
{
  const int b = blockIdx.x;
  const int e  = b / 12;
  const int nt = b % 12;
  const int count = min(counts[e], CAPE);
  if (count <= 0) return;
  const int nmt = (count + 255) >> 8;
  const int tid = threadIdx.x;
  const int estart = starts[e];

  // A[256 rows][128B] @0 (32KB), B[128 n][128B] @32768 (16KB); n = half*64 + icol
  __shared__ __align__(16) char lds[49152];

  const int lane = tid & 63, wv = tid >> 6;   // 4 waves; wave rows wv*64..+64, all 128 n

  // B staging: kg = tid>>5 (8 k each), n4 = (tid&31)*4 (covers 128 n)
  const int bkg = tid >> 5;
  const int n4  = (tid & 31) * 4;
  const int gcol = (n4 < 64) ? (nt*64 + n4) : (IDIM + nt*64 + (n4 - 64));
  const float* w13e = w13 + (size_t)e * HDIM * (2*IDIM) + gcol;

  // A gload rounds r=0..7: row = wv*64 + r*8 + (lane>>3), chunk lane&7, pre-swizzled src
  int srcch[8];
#pragma unroll
  for (int r = 0; r < 8; ++r)
    srcch[r] = (lane & 7) ^ (lane >> 3) ^ ((wv*8 + r) & 7);

  for (int mit = 0; mit < nmt; ++mit) {
    const int R0 = mit << 8;
    const int base_sorted = estart + R0;
    int tokp[8];
#pragma unroll
    for (int r = 0; r < 8; ++r) {
      int sr = base_sorted + wv*64 + r*8 + (lane >> 3);
      if (sr > NFLAT-1) sr = NFLAT-1;
      tokp[r] = row_info[sr] >> 2;
    }

    f32x4 accg[4][4], accu[4][4];
#pragma unroll
    for (int i = 0; i < 4; ++i)
#pragma unroll
      for (int j = 0; j < 4; ++j) { accg[i][j] = f32x4{0.f,0.f,0.f,0.f}; accu[i][j] = f32x4{0.f,0.f,0.f,0.f}; }

    for (int kt = 0; kt < HDIM/64; ++kt) {
      // stage B first (HBM stream — longest latency; issue before A)
      f32x4 f[8];
      {
        const float* bp = w13e + (size_t)(kt*64 + bkg*8) * (2*IDIM);
#pragma unroll
        for (int j = 0; j < 8; ++j) f[j] = *(const f32x4*)(bp + (size_t)j * (2*IDIM));
      }
      // stage A: async direct-to-LDS (8 rounds x 64 lanes x 16B = 32KB)
#pragma unroll
      for (int r = 0; r < 8; ++r)
        gload_lds16(hs_bf + (size_t)tokp[r]*HDIM + kt*64 + srcch[r]*8,
                    lds + wv*8192 + r*1024 + lane*16);
      // pack B: fp32 -> bf16 k-pair packed
      {
        char* Bl = lds + 32768;
#pragma unroll
        for (int i = 0; i < 4; ++i) {
          u32x4 q;
          q[0] = pack2(f[0][i], f[1][i]);
          q[1] = pack2(f[2][i], f[3][i]);
          q[2] = pack2(f[4][i], f[5][i]);
          q[3] = pack2(f[6][i], f[7][i]);
          *(u32x4*)(Bl + swz(n4 + i, bkg)) = q;
        }
      }
      __syncthreads();
      char* Bl = lds + 32768;
#pragma unroll
      for (int kfi = 0; kfi < 2; ++kfi) {
        const int ch = (kfi<<2) | (lane>>4);
        bf16x8 af[4], bg[4], bu[4];
#pragma unroll
        for (int m2 = 0; m2 < 4; ++m2)
          af[m2] = *(const bf16x8*)(lds + swz(wv*64 + m2*16 + (lane & 15), ch));
#pragma unroll
        for (int ni = 0; ni < 4; ++ni) {
          int ic = ni*16 + (lane & 15);
          bg[ni] = *(const bf16x8*)(Bl + swz(ic, ch));
          bu[ni] = *(const bf16x8*)(Bl + swz(64 + ic, ch));
        }
#pragma unroll
        for (int m2 = 0; m2 < 4; ++m2)
#pragma unroll
          for (int ni = 0; ni < 4; ++ni) {
            accg[m2][ni] = __builtin_amdgcn_mfma_f32_16x16x32_bf16(af[m2], bg[ni], accg[m2][ni], 0, 0, 0);
            accu[m2][ni] = __builtin_amdgcn_mfma_f32_16x16x32_bf16(af[m2], bu[ni], accu[m2][ni], 0, 0, 0);
          }
      }
      __syncthreads();
    }

    // epilogue: silu(g)*u -> a_buf (bf16)
#pragma unroll
    for (int m2 = 0; m2 < 4; ++m2) {
#pragma unroll
      for (int j = 0; j < 4; ++j) {
        int rl = wv*64 + m2*16 + (lane >> 4)*4 + j;
        if (R0 + rl < count) {
          size_t rowoff = (size_t)(base_sorted + rl) * IDIM;
#pragma unroll
          for (int ni = 0; ni < 4; ++ni) {
            int col = nt*64 + ni*16 + (lane & 15);
            float g = accg[m2][ni][j], u = accu[m2][ni][j];
            float a = (g / (1.f + __expf(-g))) * u;
            a_buf[rowoff + col] = f2bf(a);
          }
        }
      }
    }
  }
}

// ---------------- GEMM2 -> y_buf (bf16, sorted rows, unweighted) ----------------
// BM=256 x BN=128 cols, BK=64, 256 thr, 48KB LDS single-buffer, 3 blocks/CU.
// Linear block mapping (NO XCD swizzle): e = b/16, nt = b%16.
__global__ __launch_bounds__(256, 3) void k_gemm2(
    const unsigned short* __restrict__ a_buf, const float* __restrict__ w2,
    const int* __restrict__ counts, const int* __restrict__ starts,
    unsigned short* __restrict__ y_buf)
{
  const int b = blockIdx.x;
  const int e  = b >> 4;
  const int nt = b & 15;
  const int count = min(counts[e], CAPE);
  if (count <= 0) return;
  const int nmt = (count + 255) >> 8;
  const int tid = threadIdx.x;
  const int estart = starts[e];

  // A[256][128B] @0 (32KB), B[128 n][128B] @32768 (16KB)
  __shared__ __align__(16) char lds[49152];

  const int lane = tid & 63, wv = tid >> 6;

  const int bkg = tid >> 5;
  const int n4  = (tid & 31) * 4;
  const float* w2e = w2 + (size_t)e * IDIM * HDIM + (size_t)nt*128 + n4;

  int srcch[8];
#pragma unroll
  for (int r = 0; r < 8; ++r)
    srcch[r] = (lane & 7) ^ (lane >> 3) ^ ((wv*8 + r) & 7);

  for (int mit = 0; mit < nmt; ++mit) {
    const int R0 = mit << 8;
    const int base_sorted = estart + R0;
    int srp[8];
#pragma unroll
    for (int r = 0; r < 8; ++r) {
      int sr = base_sorted + wv*64 + r*8 + (lane >> 3);
      srp[r] = (sr > NFLAT-1) ? (NFLAT-1) : sr;
    }

    f32x4 acc[4][8];
#pragma unroll
    for (int i = 0; i < 4; ++i)
#pragma unroll
      for (int j = 0; j < 8; ++j) acc[i][j] = f32x4{0.f,0.f,0.f,0.f};

    for (int kt = 0; kt < IDIM/64; ++kt) {
      // stage B first (HBM stream)
      f32x4 f[8];
      {
        const float* bp = w2e + (size_t)(kt*64 + bkg*8) * HDIM;
#pragma unroll
        for (int j = 0; j < 8; ++j) f[j] = *(const f32x4*)(bp + (size_t)j * HDIM);
      }
      // stage A: async direct-to-LDS
#pragma unroll
      for (int r = 0; r < 8; ++r)
        gload_lds16(a_buf + (size_t)srp[r]*IDIM + kt*64 + srcch[r]*8,
                    lds + wv*8192 + r*1024 + lane*16);
      // pack B
      {
        char* Bl = lds + 32768;
#pragma unroll
        for (int i = 0; i < 4; ++i) {
          u32x4 q;
          q[0] = pack2(f[0][i], f[1][i]);
          q[1] = pack2(f[2][i], f[3][i]);
          q[2] = pack2(f[4][i], f[5][i]);
          q[3] = pack2(f[6][i], f[7][i]);
          *(u32x4*)(Bl + swz(n4 + i, bkg)) = q;
        }
      }
      __syncthreads();
      char* Bl = lds + 32768;
#pragma unroll
      for (int kfi = 0; kfi < 2; ++kfi) {
        const int ch = (kfi<<2) | (lane>>4);
        bf16x8 af[4], bb[8];
#pragma unroll
        for (int m2 = 0; m2 < 4; ++m2)
          af[m2] = *(const bf16x8*)(lds + swz(wv*64 + m2*16 + (lane & 15), ch));
#pragma unroll
        for (int ni = 0; ni < 8; ++ni)
          bb[ni] = *(const bf16x8*)(Bl + swz(ni*16 + (lane & 15), ch));
#pragma unroll
        for (int m2 = 0; m2 < 4; ++m2)
#pragma unroll
          for (int ni = 0; ni < 8; ++ni)
            acc[m2][ni] = __builtin_amdgcn_mfma_f32_16x16x32_bf16(af[m2], bb[ni], acc[m2][ni], 0, 0, 0);
      }
      __syncthreads();
    }

    // epilogue: bf16 stores of unweighted y rows
#pragma unroll
    for (int m2 = 0; m2 < 4; ++m2) {
#pragma unroll
      for (int j = 0; j < 4; ++j) {
        int rl = wv*64 + m2*16 + (lane >> 4)*4 + j;
        if (R0 + rl < count) {
          int sr = base_sorted + rl;
          unsigned short* yrow = y_buf + (size_t)sr * HDIM;
#pragma unroll
          for (int ni = 0; ni < 8; ++ni) {
            int col = nt*128 + ni*16 + (lane & 15);
            yrow[col] = f2bf(acc[m2][ni][j]);
          }
        }
      }
    }
  }
}

// ---------------- finalize: out[t] = sum_k tw[t,k] * y_buf[sortpos[t,k]] ----------------
__global__ __launch_bounds__(256) void k_finalize(
    const unsigned short* __restrict__ y_buf, const int* __restrict__ sortpos,
    const float* __restrict__ tw, float* __restrict__ out)
{
  const int t = blockIdx.x;
  const int tid = threadIdx.x;
  float acc[8];
#pragma unroll
  for (int i = 0; i < 8; ++i) acc[i] = 0.f;
#pragma unroll
  for (int k = 0; k < 4; ++k) {
    int sp = sortpos[t*4+k];
    float w = tw[t*4+k];
    if (sp >= 0) {
      u32x4 v = *(const u32x4*)(y_buf + (size_t)sp * HDIM + tid*8);
#pragma unroll
      for (int q = 0; q < 4; ++q) {
        float lo = __builtin_bit_cast(float, v[q] << 16);
        float hi = __builtin_bit_cast(float, v[q] & 0xffff0000u);
        acc[2*q]   += w * lo;
        acc[2*q+1] += w * hi;
      }
    }
  }
  f32x4 o0 = {acc[0], acc[1], acc[2], acc[3]};
  f32x4 o1 = {acc[4], acc[5], acc[6], acc[7]};
  f32x4* o = (f32x4*)(out + (size_t)t * HDIM + tid*8);
  o[0] = o0;
  o[1] = o1;
}

extern "C" void kernel_launch(void* const* d_in, const int* in_sizes, int n_in,
                              void* d_out, int out_size, void* d_ws, size_t ws_size,
                              hipStream_t stream) {
  const float* hs  = (const float*)d_in[0];
  const float* gw  = (const float*)d_in[1];
  const float* w13 = (const float*)d_in[2];
  const float* w2  = (const float*)d_in[3];
  float* out = (float*)d_out;

  char* ws = (char*)d_ws;
  size_t off = 0;
  auto alloc = [&](size_t bytes) {
    off = (off + 255) & ~(size_t)255;
    char* p = ws + off;
    off += bytes;
    return p;
  };
  unsigned short* hs_bf = (unsigned short*)alloc((size_t)T_TOK * HDIM * 2);
  int*   tidx   = (int*)  alloc((size_t)NFLAT * 4);
  float* tw     = (float*)alloc((size_t)NFLAT * 4);
  int*   rankb  = (int*)  alloc((size_t)NFLAT * 4);
  int*   counts = (int*)  alloc((size_t)NEXP * 4);
  int*   starts = (int*)  alloc((size_t)NEXP * 4);
  int*   rinfo  = (int*)  alloc((size_t)NFLAT * 4);
  int*   sortp  = (int*)  alloc((size_t)NFLAT * 4);
  unsigned short* a_buf = (unsigned short*)alloc((size_t)NFLAT * IDIM * 2);
  unsigned short* y_buf = (unsigned short*)alloc((size_t)NFLAT * HDIM * 2);
  (void)ws_size; (void)in_sizes; (void)n_in; (void)out_size;

  k_gating<<<T_TOK/16, 256, 0, stream>>>(hs, gw, hs_bf, tidx, tw);
  k_count_rank<<<NEXP, 64, 0, stream>>>(tidx, rankb, counts);
  k_build<<<1, 256, 0, stream>>>(tidx, rankb, counts, starts, rinfo, sortp);
  k_gemm1<<<dim3(768), 256, 0, stream>>>(hs_bf, w13, counts, starts, rinfo, a_buf);
  k_gemm2<<<dim3(1024), 256, 0, stream>>>(a_buf, w2, counts, starts, y_buf);
  k_finalize<<<T_TOK, 256, 0, stream>>>(y_buf, sortp, tw, out);
}

// Round 10
// 970.771 us; speedup vs baseline: 1.5577x; 1.5577x over previous
//
#include <hip/hip_runtime.h>
#include <hip/hip_bf16.h>

#define T_TOK 4096
#define HDIM  2048
#define NEXP  64
#define IDIM  768
#define TOPK  4
#define CAPE  512
#define NFLAT (T_TOK*TOPK)

typedef __bf16        bf16x8 __attribute__((ext_vector_type(8)));
typedef float         f32x4  __attribute__((ext_vector_type(4)));
typedef unsigned int  u32x4  __attribute__((ext_vector_type(4)));

__device__ __forceinline__ unsigned short f2bf(float f) {
  __bf16 b = (__bf16)f;
  return __builtin_bit_cast(unsigned short, b);
}
__device__ __forceinline__ unsigned pack2(float lo, float hi) {
  return (unsigned)f2bf(lo) | ((unsigned)f2bf(hi) << 16);
}
// LDS tile addressing (bytes): row stripe 128B, 16B chunk xor-swizzled
__device__ __forceinline__ int fswz(int row) { return ((row & 7) ^ ((row >> 3) & 7)) & 7; }
__device__ __forceinline__ int swz(int row, int chunk) {
  return row*128 + (((chunk ^ fswz(row)) & 7) << 4);
}
// async global->LDS, 16B/lane, linear dest
__device__ __forceinline__ void gload_lds16(const void* g, void* l) {
  __builtin_amdgcn_global_load_lds(
      (const __attribute__((address_space(1))) unsigned int*)g,
      (__attribute__((address_space(3))) unsigned int*)l, 16, 0, 0);
}

// ---------------- gating: logits, top-4, renorm weights; also hs -> bf16 ----------------
__global__ __launch_bounds__(256) void k_gating(
    const float* __restrict__ hs, const float* __restrict__ gw,
    unsigned short* __restrict__ hs_bf, int* __restrict__ tidx, float* __restrict__ tw)
{
  __shared__ float lg[16][64];
  const int tid = threadIdx.x;
  const int t0  = blockIdx.x * 16;

  {
    const f32x4* src = (const f32x4*)(hs + (size_t)t0 * HDIM);
    for (int i = tid; i < 16 * HDIM / 4; i += 256) {
      f32x4 v = src[i];
      ushort4 o;
      o.x = f2bf(v[0]); o.y = f2bf(v[1]); o.z = f2bf(v[2]); o.w = f2bf(v[3]);
      *(ushort4*)(hs_bf + (size_t)t0 * HDIM + (size_t)i * 4) = o;
    }
  }

  const int lane = tid & 63, wv = tid >> 6;
  {
    const f32x4* gr = (const f32x4*)(gw + (size_t)lane * HDIM);
    const f32x4* x0 = (const f32x4*)(hs + (size_t)(t0 + wv*4 + 0) * HDIM);
    const f32x4* x1 = (const f32x4*)(hs + (size_t)(t0 + wv*4 + 1) * HDIM);
    const f32x4* x2 = (const f32x4*)(hs + (size_t)(t0 + wv*4 + 2) * HDIM);
    const f32x4* x3 = (const f32x4*)(hs + (size_t)(t0 + wv*4 + 3) * HDIM);
    float a0=0.f, a1=0.f, a2=0.f, a3=0.f;
    for (int h = 0; h < HDIM/4; ++h) {
      f32x4 g = gr[h];
      f32x4 v0 = x0[h], v1 = x1[h], v2 = x2[h], v3 = x3[h];
      a0 += g[0]*v0[0] + g[1]*v0[1] + g[2]*v0[2] + g[3]*v0[3];
      a1 += g[0]*v1[0] + g[1]*v1[1] + g[2]*v1[2] + g[3]*v1[3];
      a2 += g[0]*v2[0] + g[1]*v2[1] + g[2]*v2[2] + g[3]*v2[3];
      a3 += g[0]*v3[0] + g[1]*v3[1] + g[2]*v3[2] + g[3]*v3[3];
    }
    lg[wv*4+0][lane] = a0;
    lg[wv*4+1][lane] = a1;
    lg[wv*4+2][lane] = a2;
    lg[wv*4+3][lane] = a3;
  }
  __syncthreads();

  if (tid < 16) {
    const int t = t0 + tid;
    unsigned long long chosen = 0ull;
    float bv[4]; int bi[4];
#pragma unroll
    for (int k = 0; k < 4; ++k) {
      float best = -1e30f; int b = 0;
      for (int e = 0; e < 64; ++e) {
        float v = lg[tid][e];
        if (!((chosen >> e) & 1ull) && v > best) { best = v; b = e; }
      }
      chosen |= 1ull << b; bv[k] = best; bi[k] = b;
    }
    float s = 0.f, w[4];
#pragma unroll
    for (int k = 0; k < 4; ++k) { w[k] = __expf(bv[k] - bv[0]); s += w[k]; }
    float inv = 1.f / s;
#pragma unroll
    for (int k = 0; k < 4; ++k) { tidx[t*4+k] = bi[k]; tw[t*4+k] = w[k] * inv; }
  }
}

// ---------------- per-expert stable rank (ballot scan) ----------------
__global__ __launch_bounds__(64) void k_count_rank(
    const int* __restrict__ tidx, int* __restrict__ rankb, int* __restrict__ counts)
{
  const int e = blockIdx.x;
  const int lane = threadIdx.x;
  int base = 0;
  for (int c = 0; c < NFLAT/64; ++c) {
    int n = c*64 + lane;
    bool m = (tidx[n] == e);
    unsigned long long mask = __ballot(m);
    if (m) rankb[n] = base + __popcll(mask & ((1ull << lane) - 1ull));
    base += __popcll(mask);
  }
  if (lane == 0) counts[e] = base;
}

// ---------------- starts scan + sorted-row maps ----------------
__global__ __launch_bounds__(256) void k_build(
    const int* __restrict__ tidx, const int* __restrict__ rankb,
    const int* __restrict__ counts,
    int* __restrict__ starts, int* __restrict__ row_info, int* __restrict__ sortpos)
{
  __shared__ int s_starts[NEXP];
  if (threadIdx.x == 0) {
    int s = 0;
    for (int e = 0; e < NEXP; ++e) { s_starts[e] = s; starts[e] = s; s += counts[e]; }
  }
  __syncthreads();
  for (int n = threadIdx.x; n < NFLAT; n += 256) {
    int e = tidx[n], r = rankb[n];
    int sr = s_starts[e] + r;
    row_info[sr] = n;
    sortpos[n] = (r < CAPE) ? sr : -1;
  }
}

// ---------------- conv13: w13 fp32 -> bf16 packed LDS-image tiles ----------------
// w13p[e][kt(32)][nt(12)][16KB]; tile = [128 n][8 chunk-slots of 16B], n<64=gate, n>=64=up.
// conv LDS float s[64][128] with column xor-swizzle (c ^ ((k>>3)<<2)) to kill pack-read conflicts.
__device__ __forceinline__ int sAddr(int k, int c) {
  return k*128 + (c ^ (((k >> 3) & 7) << 2));
}
__global__ __launch_bounds__(256) void k_conv13(
    const float* __restrict__ w13, char* __restrict__ w13p)
{
  const int kt = blockIdx.x;        // 0..31
  const int e  = blockIdx.y;        // 0..63
  const int tid = threadIdx.x;
  __shared__ float s[64*128];
  const float* we = w13 + (size_t)e * HDIM * (2*IDIM) + (size_t)kt * 64 * (2*IDIM);

  for (int cw = 0; cw < 12; ++cw) {
    __syncthreads();
    // stage 64k x 128c fp32 (coalesced)
#pragma unroll
    for (int r = 0; r < 8; ++r) {
      int idx = r*256 + tid;
      int k = idx >> 5, c4 = (idx & 31) * 4;
      f32x4 v = *(const f32x4*)(we + (size_t)k * (2*IDIM) + cw*128 + c4);
      *(f32x4*)&s[sAddr(k, c4)] = v;
    }
    __syncthreads();
    // pack into 2 half-tiles of this window
    const int uhalf = (cw >= 6);
    const int cwm = uhalf ? (cw - 6) : cw;
#pragma unroll
    for (int r = 0; r < 4; ++r) {
      int o = r*256 + tid;            // 0..1023
      int t2 = o >> 9, oo = o & 511, nn = oo >> 3, s8 = oo & 7;
      int n = nn + (uhalf ? 64 : 0);
      int nt = cwm*2 + t2;
      int ch = (s8 ^ fswz(n)) & 7;
      int c = t2*64 + nn;
      int k0 = ch*8;
      u32x4 q;
      q[0] = pack2(s[sAddr(k0+0, c)], s[sAddr(k0+1, c)]);
      q[1] = pack2(s[sAddr(k0+2, c)], s[sAddr(k0+3, c)]);
      q[2] = pack2(s[sAddr(k0+4, c)], s[sAddr(k0+5, c)]);
      q[3] = pack2(s[sAddr(k0+6, c)], s[sAddr(k0+7, c)]);
      *(u32x4*)(w13p + ((((size_t)e*32 + kt)*12 + nt) << 14) + n*128 + s8*16) = q;
    }
  }
}

// ---------------- conv2: w2 fp32 -> bf16 packed tiles ----------------
// w2p[e][kt(12)][nt(16)][16KB]; tile = [128 n][8 slots], n = col within 128-col tile.
__global__ __launch_bounds__(256) void k_conv2(
    const float* __restrict__ w2, char* __restrict__ w2p)
{
  const int kt = blockIdx.x;        // 0..11
  const int e  = blockIdx.y;        // 0..63
  const int tid = threadIdx.x;
  __shared__ float s[64*128];
  const float* we = w2 + (size_t)e * IDIM * HDIM + (size_t)kt * 64 * HDIM;

  for (int nt = 0; nt < 16; ++nt) {
    __syncthreads();
#pragma unroll
    for (int r = 0; r < 8; ++r) {
      int idx = r*256 + tid;
      int k = idx >> 5, c4 = (idx & 31) * 4;
      f32x4 v = *(const f32x4*)(we + (size_t)k * HDIM + nt*128 + c4);
      *(f32x4*)&s[sAddr(k, c4)] = v;
    }
    __syncthreads();
#pragma unroll
    for (int r = 0; r < 4; ++r) {
      int o = r*256 + tid;            // 0..1023
      int n = o >> 3, s8 = o & 7;
      int ch = (s8 ^ fswz(n)) & 7;
      int k0 = ch*8;
      u32x4 q;
      q[0] = pack2(s[sAddr(k0+0, n)], s[sAddr(k0+1, n)]);
      q[1] = pack2(s[sAddr(k0+2, n)], s[sAddr(k0+3, n)]);
      q[2] = pack2(s[sAddr(k0+4, n)], s[sAddr(k0+5, n)]);
      q[3] = pack2(s[sAddr(k0+6, n)], s[sAddr(k0+7, n)]);
      *(u32x4*)(w2p + ((((size_t)e*12 + kt)*16 + nt) << 14) + n*128 + s8*16) = q;
    }
  }
}

// ---------------- GEMM1: gather A x packed-B + SwiGLU -> a_buf (bf16) ----------------
// BM=128, tile n=128 (64 gate + 64 up icols), BK=64, 256 thr, dbuf 2x32KB, all-gload_lds,
// T3-minimum pipeline: barrier -> STAGE(next) -> compute(cur); loads fly through compute.
__global__ __launch_bounds__(256, 2) void k_gemm1(
    const unsigned short* __restrict__ hs_bf, const char* __restrict__ w13p,
    const int* __restrict__ counts, const int* __restrict__ starts,
    const int* __restrict__ row_info, unsigned short* __restrict__ a_buf)
{
  const int b = blockIdx.x;
  const int e  = b / 12;
  const int nt = b % 12;
  const int count = min(counts[e], CAPE);
  if (count <= 0) return;
  const int nmt = (count + 127) >> 7;
  const int tid = threadIdx.x;
  const int estart = starts[e];
  const int NK = HDIM/64;   // 32

  // buffer: A[128][128B] @0 (16KB), B[128n][128B] @16384 (16KB); x2
  __shared__ __align__(16) char lds[2*32768];

  const int lane = tid & 63, wv = tid >> 6;
  const int wr = wv >> 1, wc = wv & 1;

  const char* wtile = w13p + (((size_t)e*32)*12 + nt) * 16384;  // + kt*12*16384

  int srcch[4];
#pragma unroll
  for (int r = 0; r < 4; ++r)
    srcch[r] = (lane & 7) ^ (lane >> 3) ^ ((wv*4 + r) & 7);

  for (int mit = 0; mit < nmt; ++mit) {
    const int R0 = mit << 7;
    const int base_sorted = estart + R0;
    int tokp[4];
#pragma unroll
    for (int r = 0; r < 4; ++r) {
      int sr = base_sorted + wv*32 + r*8 + (lane >> 3);
      if (sr > NFLAT-1) sr = NFLAT-1;
      tokp[r] = row_info[sr] >> 2;
    }

    f32x4 accg[4][2], accu[4][2];
#pragma unroll
    for (int i = 0; i < 4; ++i)
#pragma unroll
      for (int j = 0; j < 2; ++j) { accg[i][j] = f32x4{0.f,0.f,0.f,0.f}; accu[i][j] = f32x4{0.f,0.f,0.f,0.f}; }

    auto STAGE = [&](int buf, int kt) {
      char* Al = lds + buf*32768;
      char* Bl = Al + 16384;
#pragma unroll
      for (int r = 0; r < 4; ++r)
        gload_lds16(hs_bf + (size_t)tokp[r]*HDIM + kt*64 + srcch[r]*8,
                    Al + wv*4096 + r*1024 + lane*16);
      const char* bt = wtile + (size_t)kt * (12*16384);
#pragma unroll
      for (int r = 0; r < 4; ++r)
        gload_lds16(bt + (r*256 + tid)*16, Bl + (r*256 + tid)*16);
    };

    __syncthreads();          // previous m-iter fully done with LDS
    STAGE(0, 0);
    int cur = 0;
    for (int kt = 0; kt < NK; ++kt) {
      __syncthreads();        // drains vmcnt -> buf[cur] ready
      if (kt+1 < NK) STAGE(cur^1, kt+1);   // in flight during compute
      char* Al = lds + cur*32768;
      char* Bl = Al + 16384;
#pragma unroll
      for (int kfi = 0; kfi < 2; ++kfi) {
        const int ch = (kfi<<2) | (lane>>4);
        bf16x8 af[4], bg[2], bu[2];
#pragma unroll
        for (int m2 = 0; m2 < 4; ++m2)
          af[m2] = *(const bf16x8*)(Al + swz(wr*64 + m2*16 + (lane & 15), ch));
#pragma unroll
        for (int ni = 0; ni < 2; ++ni) {
          int ic = wc*32 + ni*16 + (lane & 15);
          bg[ni] = *(const bf16x8*)(Bl + swz(ic, ch));
          bu[ni] = *(const bf16x8*)(Bl + swz(64 + ic, ch));
        }
#pragma unroll
        for (int m2 = 0; m2 < 4; ++m2)
#pragma unroll
          for (int ni = 0; ni < 2; ++ni) {
            accg[m2][ni] = __builtin_amdgcn_mfma_f32_16x16x32_bf16(af[m2], bg[ni], accg[m2][ni], 0, 0, 0);
            accu[m2][ni] = __builtin_amdgcn_mfma_f32_16x16x32_bf16(af[m2], bu[ni], accu[m2][ni], 0, 0, 0);
          }
      }
      cur ^= 1;
    }

    // epilogue: silu(g)*u -> a_buf
#pragma unroll
    for (int m2 = 0; m2 < 4; ++m2) {
#pragma unroll
      for (int j = 0; j < 4; ++j) {
        int rl = wr*64 + m2*16 + (lane >> 4)*4 + j;
        if (R0 + rl < count) {
          size_t rowoff = (size_t)(base_sorted + rl) * IDIM;
#pragma unroll
          for (int ni = 0; ni < 2; ++ni) {
            int col = nt*64 + wc*32 + ni*16 + (lane & 15);
            float g = accg[m2][ni][j], u = accu[m2][ni][j];
            float a = (g / (1.f + __expf(-g))) * u;
            a_buf[rowoff + col] = f2bf(a);
          }
        }
      }
    }
  }
}

// ---------------- GEMM2: a_buf x packed-w2 -> y_buf (bf16) ----------------
// BM=128, BN=128, BK=64, 256 thr, dbuf 2x32KB, all-gload_lds, same pipeline.
__global__ __launch_bounds__(256, 2) void k_gemm2(
    const unsigned short* __restrict__ a_buf, const char* __restrict__ w2p,
    const int* __restrict__ counts, const int* __restrict__ starts,
    unsigned short* __restrict__ y_buf)
{
  const int b = blockIdx.x;
  const int e  = b >> 4;
  const int nt = b & 15;
  const int count = min(counts[e], CAPE);
  if (count <= 0) return;
  const int nmt = (count + 127) >> 7;
  const int tid = threadIdx.x;
  const int estart = starts[e];
  const int NK = IDIM/64;   // 12

  __shared__ __align__(16) char lds[2*32768];

  const int lane = tid & 63, wv = tid >> 6;
  const int wr = wv >> 1, wc = wv & 1;

  const char* wtile = w2p + (((size_t)e*12)*16 + nt) * 16384;   // + kt*16*16384

  int srcch[4];
#pragma unroll
  for (int r = 0; r < 4; ++r)
    srcch[r] = (lane & 7) ^ (lane >> 3) ^ ((wv*4 + r) & 7);

  for (int mit = 0; mit < nmt; ++mit) {
    const int R0 = mit << 7;
    const int base_sorted = estart + R0;
    int srp[4];
#pragma unroll
    for (int r = 0; r < 4; ++r) {
      int sr = base_sorted + wv*32 + r*8 + (lane >> 3);
      srp[r] = (sr > NFLAT-1) ? (NFLAT-1) : sr;
    }

    f32x4 acc[4][4];
#pragma unroll
    for (int i = 0; i < 4; ++i)
#pragma unroll
      for (int j = 0; j < 4; ++j) acc[i][j] = f32x4{0.f,0.f,0.f,0.f};

    auto STAGE = [&](int buf, int kt) {
      char* Al = lds + buf*32768;
      char* Bl = Al + 16384;
#pragma unroll
      for (int r = 0; r < 4; ++r)
        gload_lds16(a_buf + (size_t)srp[r]*IDIM + kt*64 + srcch[r]*8,
                    Al + wv*4096 + r*1024 + lane*16);
      const char* bt = wtile + (size_t)kt * (16*16384);
#pragma unroll
      for (int r = 0; r < 4; ++r)
        gload_lds16(bt + (r*256 + tid)*16, Bl + (r*256 + tid)*16);
    };

    __syncthreads();
    STAGE(0, 0);
    int cur = 0;
    for (int kt = 0; kt < NK; ++kt) {
      __syncthreads();
      if (kt+1 < NK) STAGE(cur^1, kt+1);
      char* Al = lds + cur*32768;
      char* Bl = Al + 16384;
#pragma unroll
      for (int kfi = 0; kfi < 2; ++kfi) {
        const int ch = (kfi<<2) | (lane>>4);
        bf16x8 af[4], bb[4];
#pragma unroll
        for (int m2 = 0; m2 < 4; ++m2)
          af[m2] = *(const bf16x8*)(Al + swz(wr*64 + m2*16 + (lane & 15), ch));
#pragma unroll
        for (int ni = 0; ni < 4; ++ni)
          bb[ni] = *(const bf16x8*)(Bl + swz(wc*64 + ni*16 + (lane & 15), ch));
#pragma unroll
        for (int m2 = 0; m2 < 4; ++m2)
#pragma unroll
          for (int ni = 0; ni < 4; ++ni)
            acc[m2][ni] = __builtin_amdgcn_mfma_f32_16x16x32_bf16(af[m2], bb[ni], acc[m2][ni], 0, 0, 0);
      }
      cur ^= 1;
    }

    // epilogue: bf16 stores of unweighted y rows
#pragma unroll
    for (int m2 = 0; m2 < 4; ++m2) {
#pragma unroll
      for (int j = 0; j < 4; ++j) {
        int rl = wr*64 + m2*16 + (lane >> 4)*4 + j;
        if (R0 + rl < count) {
          int sr = base_sorted + rl;
          unsigned short* yrow = y_buf + (size_t)sr * HDIM;
#pragma unroll
          for (int ni = 0; ni < 4; ++ni) {
            int col = nt*128 + wc*64 + ni*16 + (lane & 15);
            yrow[col] = f2bf(acc[m2][ni][j]);
          }
        }
      }
    }
  }
}

// ---------------- finalize: out[t] = sum_k tw[t,k] * y_buf[sortpos[t,k]] ----------------
__global__ __launch_bounds__(256) void k_finalize(
    const unsigned short* __restrict__ y_buf, const int* __restrict__ sortpos,
    const float* __restrict__ tw, float* __restrict__ out)
{
  const int t = blockIdx.x;
  const int tid = threadIdx.x;
  float acc[8];
#pragma unroll
  for (int i = 0; i < 8; ++i) acc[i] = 0.f;
#pragma unroll
  for (int k = 0; k < 4; ++k) {
    int sp = sortpos[t*4+k];
    float w = tw[t*4+k];
    if (sp >= 0) {
      u32x4 v = *(const u32x4*)(y_buf + (size_t)sp * HDIM + tid*8);
#pragma unroll
      for (int q = 0; q < 4; ++q) {
        float lo = __builtin_bit_cast(float, v[q] << 16);
        float hi = __builtin_bit_cast(float, v[q] & 0xffff0000u);
        acc[2*q]   += w * lo;
        acc[2*q+1] += w * hi;
      }
    }
  }
  f32x4 o0 = {acc[0], acc[1], acc[2], acc[3]};
  f32x4 o1 = {acc[4], acc[5], acc[6], acc[7]};
  f32x4* o = (f32x4*)(out + (size_t)t * HDIM + tid*8);
  o[0] = o0;
  o[1] = o1;
}

extern "C" void kernel_launch(void* const* d_in, const int* in_sizes, int n_in,
                              void* d_out, int out_size, void* d_ws, size_t ws_size,
                              hipStream_t stream) {
  const float* hs  = (const float*)d_in[0];
  const float* gw  = (const float*)d_in[1];
  const float* w13 = (const float*)d_in[2];
  const float* w2  = (const float*)d_in[3];
  float* out = (float*)d_out;

  char* ws = (char*)d_ws;
  size_t off = 0;
  auto alloc = [&](size_t bytes) {
    off = (off + 255) & ~(size_t)255;
    char* p = ws + off;
    off += bytes;
    return p;
  };
  unsigned short* hs_bf = (unsigned short*)alloc((size_t)T_TOK * HDIM * 2);
  int*   tidx   = (int*)  alloc((size_t)NFLAT * 4);
  float* tw     = (float*)alloc((size_t)NFLAT * 4);
  int*   rankb  = (int*)  alloc((size_t)NFLAT * 4);
  int*   counts = (int*)  alloc((size_t)NEXP * 4);
  int*   starts = (int*)  alloc((size_t)NEXP * 4);
  int*   rinfo  = (int*)  alloc((size_t)NFLAT * 4);
  int*   sortp  = (int*)  alloc((size_t)NFLAT * 4);
  unsigned short* a_buf = (unsigned short*)alloc((size_t)NFLAT * IDIM * 2);
  unsigned short* y_buf = (unsigned short*)alloc((size_t)NFLAT * HDIM * 2);
  char* w13p = (char*)alloc((size_t)NEXP * 32 * 12 * 16384);   // 403 MB
  char* w2p  = (char*)alloc((size_t)NEXP * 12 * 16 * 16384);   // 201 MB
  (void)ws_size; (void)in_sizes; (void)n_in; (void)out_size;

  k_conv13<<<dim3(32, NEXP), 256, 0, stream>>>(w13, w13p);
  k_conv2 <<<dim3(12, NEXP), 256, 0, stream>>>(w2, w2p);
  k_gating<<<T_TOK/16, 256, 0, stream>>>(hs, gw, hs_bf, tidx, tw);
  k_count_rank<<<NEXP, 64, 0, stream>>>(tidx, rankb, counts);
  k_build<<<1, 256, 0, stream>>>(tidx, rankb, counts, starts, rinfo, sortp);
  k_gemm1<<<dim3(12*NEXP), 256, 0, stream>>>(hs_bf, w13p, counts, starts, rinfo, a_buf);
  k_gemm2<<<dim3(16*NEXP), 256, 0, stream>>>(a_buf, w2p, counts, starts, y_buf);
  k_finalize<<<T_TOK, 256, 0, stream>>>(y_buf, sortp, tw, out);
}

// Round 11
// 843.209 us; speedup vs baseline: 1.7933x; 1.1513x over previous
//
#include <hip/hip_runtime.h>
#include <hip/hip_bf16.h>

#define T_TOK 4096
#define HDIM  2048
#define NEXP  64
#define IDIM  768
#define TOPK  4
#define CAPE  512
#define NFLAT (T_TOK*TOPK)

typedef __bf16        bf16x8 __attribute__((ext_vector_type(8)));
typedef float         f32x4  __attribute__((ext_vector_type(4)));
typedef unsigned int  u32x4  __attribute__((ext_vector_type(4)));

__device__ __forceinline__ unsigned short f2bf(float f) {
  __bf16 b = (__bf16)f;
  return __builtin_bit_cast(unsigned short, b);
}
__device__ __forceinline__ unsigned pack2(float lo, float hi) {
  return (unsigned)f2bf(lo) | ((unsigned)f2bf(hi) << 16);
}
__device__ __forceinline__ int fswz(int row) { return ((row & 7) ^ ((row >> 3) & 7)) & 7; }
__device__ __forceinline__ int swz(int row, int chunk) {
  return row*128 + (((chunk ^ fswz(row)) & 7) << 4);
}
__device__ __forceinline__ void gload_lds16(const void* g, void* l) {
  __builtin_amdgcn_global_load_lds(
      (const __attribute__((address_space(1))) unsigned int*)g,
      (__attribute__((address_space(3))) unsigned int*)l, 16, 0, 0);
}

// ---------------- gating ----------------
__global__ __launch_bounds__(256) void k_gating(
    const float* __restrict__ hs, const float* __restrict__ gw,
    unsigned short* __restrict__ hs_bf, int* __restrict__ tidx, float* __restrict__ tw)
{
  __shared__ float lg[16][64];
  const int tid = threadIdx.x;
  const int t0  = blockIdx.x * 16;

  {
    const f32x4* src = (const f32x4*)(hs + (size_t)t0 * HDIM);
    for (int i = tid; i < 16 * HDIM / 4; i += 256) {
      f32x4 v = src[i];
      ushort4 o;
      o.x = f2bf(v[0]); o.y = f2bf(v[1]); o.z = f2bf(v[2]); o.w = f2bf(v[3]);
      *(ushort4*)(hs_bf + (size_t)t0 * HDIM + (size_t)i * 4) = o;
    }
  }

  const int lane = tid & 63, wv = tid >> 6;
  {
    const f32x4* gr = (const f32x4*)(gw + (size_t)lane * HDIM);
    const f32x4* x0 = (const f32x4*)(hs + (size_t)(t0 + wv*4 + 0) * HDIM);
    const f32x4* x1 = (const f32x4*)(hs + (size_t)(t0 + wv*4 + 1) * HDIM);
    const f32x4* x2 = (const f32x4*)(hs + (size_t)(t0 + wv*4 + 2) * HDIM);
    const f32x4* x3 = (const f32x4*)(hs + (size_t)(t0 + wv*4 + 3) * HDIM);
    float a0=0.f, a1=0.f, a2=0.f, a3=0.f;
    for (int h = 0; h < HDIM/4; ++h) {
      f32x4 g = gr[h];
      f32x4 v0 = x0[h], v1 = x1[h], v2 = x2[h], v3 = x3[h];
      a0 += g[0]*v0[0] + g[1]*v0[1] + g[2]*v0[2] + g[3]*v0[3];
      a1 += g[0]*v1[0] + g[1]*v1[1] + g[2]*v1[2] + g[3]*v1[3];
      a2 += g[0]*v2[0] + g[1]*v2[1] + g[2]*v2[2] + g[3]*v2[3];
      a3 += g[0]*v3[0] + g[1]*v3[1] + g[2]*v3[2] + g[3]*v3[3];
    }
    lg[wv*4+0][lane] = a0;
    lg[wv*4+1][lane] = a1;
    lg[wv*4+2][lane] = a2;
    lg[wv*4+3][lane] = a3;
  }
  __syncthreads();

  if (tid < 16) {
    const int t = t0 + tid;
    unsigned long long chosen = 0ull;
    float bv[4]; int bi[4];
#pragma unroll
    for (int k = 0; k < 4; ++k) {
      float best = -1e30f; int b = 0;
      for (int e = 0; e < 64; ++e) {
        float v = lg[tid][e];
        if (!((chosen >> e) & 1ull) && v > best) { best = v; b = e; }
      }
      chosen |= 1ull << b; bv[k] = best; bi[k] = b;
    }
    float s = 0.f, w[4];
#pragma unroll
    for (int k = 0; k < 4; ++k) { w[k] = __expf(bv[k] - bv[0]); s += w[k]; }
    float inv = 1.f / s;
#pragma unroll
    for (int k = 0; k < 4; ++k) { tidx[t*4+k] = bi[k]; tw[t*4+k] = w[k] * inv; }
  }
}

// ---------------- per-expert stable rank ----------------
__global__ __launch_bounds__(64) void k_count_rank(
    const int* __restrict__ tidx, int* __restrict__ rankb, int* __restrict__ counts)
{
  const int e = blockIdx.x;
  const int lane = threadIdx.x;
  int base = 0;
  for (int c = 0; c < NFLAT/64; ++c) {
    int n = c*64 + lane;
    bool m = (tidx[n] == e);
    unsigned long long mask = __ballot(m);
    if (m) rankb[n] = base + __popcll(mask & ((1ull << lane) - 1ull));
    base += __popcll(mask);
  }
  if (lane == 0) counts[e] = base;
}

// ---------------- starts + maps ----------------
__global__ __launch_bounds__(256) void k_build(
    const int* __restrict__ tidx, const int* __restrict__ rankb,
    const int* __restrict__ counts,
    int* __restrict__ starts, int* __restrict__ row_info, int* __restrict__ sortpos)
{
  __shared__ int s_starts[NEXP];
  if (threadIdx.x == 0) {
    int s = 0;
    for (int e = 0; e < NEXP; ++e) { s_starts[e] = s; starts[e] = s; s += counts[e]; }
  }
  __syncthreads();
  for (int n = threadIdx.x; n < NFLAT; n += 256) {
    int e = tidx[n], r = rankb[n];
    int sr = s_starts[e] + r;
    row_info[sr] = n;
    sortpos[n] = (r < CAPE) ? sr : -1;
  }
}

// ---------------- GEMM1: BM=256 x 64 icols x {g,u}, BK=64, 512 thr ----------------
// Pipelined: gload_lds both operands (B raw fp32), counted vmcnt + raw barriers,
// PACK phase converts fp32->bf16 in LDS; A-frags fetched to regs in PACK phase.
__global__ __launch_bounds__(512, 1) void k_gemm1(
    const unsigned short* __restrict__ hs_bf, const float* __restrict__ w13,
    const int* __restrict__ counts, const int* __restrict__ starts,
    const int* __restrict__ row_info, unsigned short* __restrict__ a_buf)
{
  const int b = blockIdx.x;
  const int e  = b / 12;
  const int nt = b % 12;
  const int count = min(counts[e], CAPE);
  if (count <= 0) return;
  const int nmt = (count + 255) >> 8;
  const int tid = threadIdx.x;
  const int estart = starts[e];
  const int NK = HDIM/64;   // 32

  // A bf16 [256][128B] x2 @0; Braw fp32 [64k][512B] x2 @65536; Bpk bf16 [128n][128B] @131072
  __shared__ __align__(16) char lds[147456];

  const int lane = tid & 63, wv = tid >> 6;
  const int wr = wv >> 1, wc = wv & 1;     // 4M x 2N wave grid

  // A staging (4 rounds): row = wv*32 + r*8 + (lane>>3)
  int srcch[4];
#pragma unroll
  for (int r = 0; r < 4; ++r)
    srcch[r] = (lane & 7) ^ (lane >> 3) ^ ((wv*4 + r) & 7);

  // B staging (4 rounds): k = wv*8 + r*2 + (lane>>5), 16B = 4 cols at gcol
  const int n4 = (lane & 31) * 4;
  const int gcol = (n4 < 64) ? (nt*64 + n4) : (IDIM + nt*64 + (n4 - 64));
  const float* w13e = w13 + (size_t)e * HDIM * (2*IDIM) + gcol;

  // PACK coords: col pn, slots ps, ps+1  (k = ps*8 .. ps*8+15)
  const int pn = tid >> 2;
  const int ps = (tid & 3) * 2;

  for (int mit = 0; mit < nmt; ++mit) {
    const int R0 = mit << 8;
    const int base_sorted = estart + R0;
    int tokp[4];
#pragma unroll
    for (int r = 0; r < 4; ++r) {
      int sr = base_sorted + wv*32 + r*8 + (lane >> 3);
      if (sr > NFLAT-1) sr = NFLAT-1;
      tokp[r] = row_info[sr] >> 2;
    }

    f32x4 accg[4][2], accu[4][2];
#pragma unroll
    for (int i = 0; i < 4; ++i)
#pragma unroll
      for (int j = 0; j < 2; ++j) { accg[i][j] = f32x4{0.f,0.f,0.f,0.f}; accu[i][j] = f32x4{0.f,0.f,0.f,0.f}; }

    auto STAGE = [&](int p, int kt) {
      char* Al = lds + p*32768;
      char* Rl = lds + 65536 + p*32768;
#pragma unroll
      for (int r = 0; r < 4; ++r)
        gload_lds16(hs_bf + (size_t)tokp[r]*HDIM + kt*64 + srcch[r]*8,
                    Al + wv*4096 + r*1024 + lane*16);
#pragma unroll
      for (int r = 0; r < 4; ++r)
        gload_lds16(w13e + (size_t)(kt*64 + wv*8 + r*2 + (lane>>5)) * (2*IDIM),
                    Rl + (wv*8 + r*2 + (lane>>5))*512 + (lane & 31)*16);
    };

    STAGE(0, 0);
    for (int kt = 0; kt < NK; ++kt) {
      const int p = kt & 1;
      if (kt+1 < NK) {
        STAGE(p^1, kt+1);
        asm volatile("s_waitcnt vmcnt(8)" ::: "memory");
      } else {
        asm volatile("s_waitcnt vmcnt(0)" ::: "memory");
      }
      __builtin_amdgcn_s_barrier();     // bar1: tile kt arrived

      // PACK: Braw(p) fp32 -> Bpk bf16 (k-pair packed, swizzled)
      {
        const char* Rl = lds + 65536 + p*32768;
        char* Bpk = lds + 131072;
        float pf[16];
#pragma unroll
        for (int j = 0; j < 16; ++j)
          pf[j] = *(const float*)(Rl + (ps*8 + j)*512 + pn*4);
        u32x4 q0, q1;
        q0[0] = pack2(pf[0],pf[1]);  q0[1] = pack2(pf[2],pf[3]);
        q0[2] = pack2(pf[4],pf[5]);  q0[3] = pack2(pf[6],pf[7]);
        q1[0] = pack2(pf[8],pf[9]);  q1[1] = pack2(pf[10],pf[11]);
        q1[2] = pack2(pf[12],pf[13]); q1[3] = pack2(pf[14],pf[15]);
        *(u32x4*)(Bpk + swz(pn, ps))   = q0;
        *(u32x4*)(Bpk + swz(pn, ps+1)) = q1;
      }
      // A-frags -> regs during PACK phase (A(p) ready; retired before bar2)
      bf16x8 af[2][4];
      {
        const char* Al = lds + p*32768;
#pragma unroll
        for (int kfi = 0; kfi < 2; ++kfi)
#pragma unroll
          for (int m2 = 0; m2 < 4; ++m2)
            af[kfi][m2] = *(const bf16x8*)(Al + swz(wr*64 + m2*16 + (lane & 15), (kfi<<2)|(lane>>4)));
      }
      asm volatile("s_waitcnt lgkmcnt(0)" ::: "memory");
      __builtin_amdgcn_s_barrier();     // bar2: Bpk visible, A-frags in regs

      const char* Bpk = lds + 131072;
#pragma unroll
      for (int kfi = 0; kfi < 2; ++kfi) {
        const int ch = (kfi<<2) | (lane>>4);
        bf16x8 bg[2], bu[2];
#pragma unroll
        for (int ni = 0; ni < 2; ++ni) {
          int ic = wc*32 + ni*16 + (lane & 15);
          bg[ni] = *(const bf16x8*)(Bpk + swz(ic, ch));
          bu[ni] = *(const bf16x8*)(Bpk + swz(64 + ic, ch));
        }
#pragma unroll
        for (int m2 = 0; m2 < 4; ++m2)
#pragma unroll
          for (int ni = 0; ni < 2; ++ni) {
            accg[m2][ni] = __builtin_amdgcn_mfma_f32_16x16x32_bf16(af[kfi][m2], bg[ni], accg[m2][ni], 0, 0, 0);
            accu[m2][ni] = __builtin_amdgcn_mfma_f32_16x16x32_bf16(af[kfi][m2], bu[ni], accu[m2][ni], 0, 0, 0);
          }
      }
    }

    // epilogue: silu(g)*u -> a_buf
#pragma unroll
    for (int m2 = 0; m2 < 4; ++m2) {
#pragma unroll
      for (int j = 0; j < 4; ++j) {
        int rl = wr*64 + m2*16 + (lane >> 4)*4 + j;
        if (R0 + rl < count) {
          size_t rowoff = (size_t)(base_sorted + rl) * IDIM;
#pragma unroll
          for (int ni = 0; ni < 2; ++ni) {
            int col = nt*64 + wc*32 + ni*16 + (lane & 15);
            float g = accg[m2][ni][j], u = accu[m2][ni][j];
            float a = (g / (1.f + __expf(-g))) * u;
            a_buf[rowoff + col] = f2bf(a);
          }
        }
      }
    }
  }
}

// ---------------- GEMM2: BM=256 x BN=128, BK=64, 512 thr, same pipeline ----------------
__global__ __launch_bounds__(512, 1) void k_gemm2(
    const unsigned short* __restrict__ a_buf, const float* __restrict__ w2,
    const int* __restrict__ counts, const int* __restrict__ starts,
    unsigned short* __restrict__ y_buf)
{
  const int b = blockIdx.x;
  const int e  = b >> 4;
  const int nt = b & 15;
  const int count = min(counts[e], CAPE);
  if (count <= 0) return;
  const int nmt = (count + 255) >> 8;
  const int tid = threadIdx.x;
  const int estart = starts[e];
  const int NK = IDIM/64;   // 12

  __shared__ __align__(16) char lds[147456];

  const int lane = tid & 63, wv = tid >> 6;
  const int wr = wv >> 1, wc = wv & 1;

  int srcch[4];
#pragma unroll
  for (int r = 0; r < 4; ++r)
    srcch[r] = (lane & 7) ^ (lane >> 3) ^ ((wv*4 + r) & 7);

  const int n4 = (lane & 31) * 4;
  const float* w2e = w2 + (size_t)e * IDIM * HDIM + (size_t)nt*128 + n4;

  const int pn = tid >> 2;
  const int ps = (tid & 3) * 2;

  for (int mit = 0; mit < nmt; ++mit) {
    const int R0 = mit << 8;
    const int base_sorted = estart + R0;
    int srp[4];
#pragma unroll
    for (int r = 0; r < 4; ++r) {
      int sr = base_sorted + wv*32 + r*8 + (lane >> 3);
      srp[r] = (sr > NFLAT-1) ? (NFLAT-1) : sr;
    }

    f32x4 acc[4][4];
#pragma unroll
    for (int i = 0; i < 4; ++i)
#pragma unroll
      for (int j = 0; j < 4; ++j) acc[i][j] = f32x4{0.f,0.f,0.f,0.f};

    auto STAGE = [&](int p, int kt) {
      char* Al = lds + p*32768;
      char* Rl = lds + 65536 + p*32768;
#pragma unroll
      for (int r = 0; r < 4; ++r)
        gload_lds16(a_buf + (size_t)srp[r]*IDIM + kt*64 + srcch[r]*8,
                    Al + wv*4096 + r*1024 + lane*16);
#pragma unroll
      for (int r = 0; r < 4; ++r)
        gload_lds16(w2e + (size_t)(kt*64 + wv*8 + r*2 + (lane>>5)) * HDIM,
                    Rl + (wv*8 + r*2 + (lane>>5))*512 + (lane & 31)*16);
    };

    STAGE(0, 0);
    for (int kt = 0; kt < NK; ++kt) {
      const int p = kt & 1;
      if (kt+1 < NK) {
        STAGE(p^1, kt+1);
        asm volatile("s_waitcnt vmcnt(8)" ::: "memory");
      } else {
        asm volatile("s_waitcnt vmcnt(0)" ::: "memory");
      }
      __builtin_amdgcn_s_barrier();

      {
        const char* Rl = lds + 65536 + p*32768;
        char* Bpk = lds + 131072;
        float pf[16];
#pragma unroll
        for (int j = 0; j < 16; ++j)
          pf[j] = *(const float*)(Rl + (ps*8 + j)*512 + pn*4);
        u32x4 q0, q1;
        q0[0] = pack2(pf[0],pf[1]);  q0[1] = pack2(pf[2],pf[3]);
        q0[2] = pack2(pf[4],pf[5]);  q0[3] = pack2(pf[6],pf[7]);
        q1[0] = pack2(pf[8],pf[9]);  q1[1] = pack2(pf[10],pf[11]);
        q1[2] = pack2(pf[12],pf[13]); q1[3] = pack2(pf[14],pf[15]);
        *(u32x4*)(Bpk + swz(pn, ps))   = q0;
        *(u32x4*)(Bpk + swz(pn, ps+1)) = q1;
      }
      bf16x8 af[2][4];
      {
        const char* Al = lds + p*32768;
#pragma unroll
        for (int kfi = 0; kfi < 2; ++kfi)
#pragma unroll
          for (int m2 = 0; m2 < 4; ++m2)
            af[kfi][m2] = *(const bf16x8*)(Al + swz(wr*64 + m2*16 + (lane & 15), (kfi<<2)|(lane>>4)));
      }
      asm volatile("s_waitcnt lgkmcnt(0)" ::: "memory");
      __builtin_amdgcn_s_barrier();

      const char* Bpk = lds + 131072;
#pragma unroll
      for (int kfi = 0; kfi < 2; ++kfi) {
        const int ch = (kfi<<2) | (lane>>4);
        bf16x8 bb[4];
#pragma unroll
        for (int ni = 0; ni < 4; ++ni)
          bb[ni] = *(const bf16x8*)(Bpk + swz(wc*64 + ni*16 + (lane & 15), ch));
#pragma unroll
        for (int m2 = 0; m2 < 4; ++m2)
#pragma unroll
          for (int ni = 0; ni < 4; ++ni)
            acc[m2][ni] = __builtin_amdgcn_mfma_f32_16x16x32_bf16(af[kfi][m2], bb[ni], acc[m2][ni], 0, 0, 0);
      }
    }

    // epilogue: bf16 stores of unweighted y rows
#pragma unroll
    for (int m2 = 0; m2 < 4; ++m2) {
#pragma unroll
      for (int j = 0; j < 4; ++j) {
        int rl = wr*64 + m2*16 + (lane >> 4)*4 + j;
        if (R0 + rl < count) {
          int sr = base_sorted + rl;
          unsigned short* yrow = y_buf + (size_t)sr * HDIM;
#pragma unroll
          for (int ni = 0; ni < 4; ++ni) {
            int col = nt*128 + wc*64 + ni*16 + (lane & 15);
            yrow[col] = f2bf(acc[m2][ni][j]);
          }
        }
      }
    }
  }
}

// ---------------- finalize ----------------
__global__ __launch_bounds__(256) void k_finalize(
    const unsigned short* __restrict__ y_buf, const int* __restrict__ sortpos,
    const float* __restrict__ tw, float* __restrict__ out)
{
  const int t = blockIdx.x;
  const int tid = threadIdx.x;
  float acc[8];
#pragma unroll
  for (int i = 0; i < 8; ++i) acc[i] = 0.f;
#pragma unroll
  for (int k = 0; k < 4; ++k) {
    int sp = sortpos[t*4+k];
    float w = tw[t*4+k];
    if (sp >= 0) {
      u32x4 v = *(const u32x4*)(y_buf + (size_t)sp * HDIM + tid*8);
#pragma unroll
      for (int q = 0; q < 4; ++q) {
        float lo = __builtin_bit_cast(float, v[q] << 16);
        float hi = __builtin_bit_cast(float, v[q] & 0xffff0000u);
        acc[2*q]   += w * lo;
        acc[2*q+1] += w * hi;
      }
    }
  }
  f32x4 o0 = {acc[0], acc[1], acc[2], acc[3]};
  f32x4 o1 = {acc[4], acc[5], acc[6], acc[7]};
  f32x4* o = (f32x4*)(out + (size_t)t * HDIM + tid*8);
  o[0] = o0;
  o[1] = o1;
}

extern "C" void kernel_launch(void* const* d_in, const int* in_sizes, int n_in,
                              void* d_out, int out_size, void* d_ws, size_t ws_size,
                              hipStream_t stream) {
  const float* hs  = (const float*)d_in[0];
  const float* gw  = (const float*)d_in[1];
  const float* w13 = (const float*)d_in[2];
  const float* w2  = (const float*)d_in[3];
  float* out = (float*)d_out;

  char* ws = (char*)d_ws;
  size_t off = 0;
  auto alloc = [&](size_t bytes) {
    off = (off + 255) & ~(size_t)255;
    char* p = ws + off;
    off += bytes;
    return p;
  };
  unsigned short* hs_bf = (unsigned short*)alloc((size_t)T_TOK * HDIM * 2);
  int*   tidx   = (int*)  alloc((size_t)NFLAT * 4);
  float* tw     = (float*)alloc((size_t)NFLAT * 4);
  int*   rankb  = (int*)  alloc((size_t)NFLAT * 4);
  int*   counts = (int*)  alloc((size_t)NEXP * 4);
  int*   starts = (int*)  alloc((size_t)NEXP * 4);
  int*   rinfo  = (int*)  alloc((size_t)NFLAT * 4);
  int*   sortp  = (int*)  alloc((size_t)NFLAT * 4);
  unsigned short* a_buf = (unsigned short*)alloc((size_t)NFLAT * IDIM * 2);
  unsigned short* y_buf = (unsigned short*)alloc((size_t)NFLAT * HDIM * 2);
  (void)ws_size; (void)in_sizes; (void)n_in; (void)out_size;

  k_gating<<<T_TOK/16, 256, 0, stream>>>(hs, gw, hs_bf, tidx, tw);
  k_count_rank<<<NEXP, 64, 0, stream>>>(tidx, rankb, counts);
  k_build<<<1, 256, 0, stream>>>(tidx, rankb, counts, starts, rinfo, sortp);
  k_gemm1<<<dim3(12*NEXP), 512, 0, stream>>>(hs_bf, w13, counts, starts, rinfo, a_buf);
  k_gemm2<<<dim3(16*NEXP), 512, 0, stream>>>(a_buf, w2, counts, starts, y_buf);
  k_finalize<<<T_TOK, 256, 0, stream>>>(y_buf, sortp, tw, out);
}